// Round 1
// baseline (1206.033 us; speedup 1.0000x reference)
//
#include <hip/hip_runtime.h>

#define N_NODES 150000
#define N_EDGES 2400000
#define F_IN    22
#define HID     32
#define N_CLS   6
#define BN_EPS  1e-5f

// ---------------------------------------------------------------------------
// K1: in-degree count over dst (self-loop handled as +1 at dis computation)
// ---------------------------------------------------------------------------
__global__ void count_deg_kernel(const int* __restrict__ dst,
                                 int* __restrict__ cnt) {
    int i = blockIdx.x * blockDim.x + threadIdx.x;
    int stride = gridDim.x * blockDim.x;
    for (; i < N_EDGES; i += stride)
        atomicAdd(&cnt[dst[i]], 1);
}

// ---------------------------------------------------------------------------
// K2: per-node h = relu(x@W_emb + b_emb) @ W_gcn ; dis = rsqrt(1+cnt);
//     hs = h * dis   (pre-scaled by source-side norm factor)
// ---------------------------------------------------------------------------
__global__ void embed_kernel(const float* __restrict__ x,
                             const float* __restrict__ W_emb,
                             const float* __restrict__ b_emb,
                             const float* __restrict__ W_gcn,
                             const int*   __restrict__ cnt,
                             float* __restrict__ hs,
                             float* __restrict__ dis) {
    __shared__ float sWe[F_IN * HID];
    __shared__ float sbe[HID];
    __shared__ float sWg[HID * HID];
    for (int t = threadIdx.x; t < F_IN * HID; t += blockDim.x) sWe[t] = W_emb[t];
    if (threadIdx.x < HID) sbe[threadIdx.x] = b_emb[threadIdx.x];
    for (int t = threadIdx.x; t < HID * HID; t += blockDim.x) sWg[t] = W_gcn[t];
    __syncthreads();

    int i = blockIdx.x * blockDim.x + threadIdx.x;
    if (i >= N_NODES) return;

    float xi[F_IN];
#pragma unroll
    for (int f = 0; f < F_IN; ++f) xi[f] = x[(size_t)i * F_IN + f];

    float h1[HID];
#pragma unroll
    for (int j = 0; j < HID; ++j) {
        float acc = sbe[j];
#pragma unroll
        for (int f = 0; f < F_IN; ++f) acc = fmaf(xi[f], sWe[f * HID + j], acc);
        h1[j] = fmaxf(acc, 0.0f);
    }

    float d = rsqrtf(1.0f + (float)cnt[i]);   // deg = 1 (self-loop) + in-count
    dis[i] = d;

#pragma unroll
    for (int j = 0; j < HID; ++j) {
        float acc = 0.0f;
#pragma unroll
        for (int f = 0; f < HID; ++f) acc = fmaf(h1[f], sWg[f * HID + j], acc);
        hs[(size_t)i * HID + j] = acc * d;
    }
}

// ---------------------------------------------------------------------------
// K3: scatter  agg[dst] += hs[src] * dis[dst]
//     items: [0,E) real edges, [E, E+N) self-loops (src=dst=i, same formula)
//     8 threads per item, each handles a float4 chunk (4 features)
// ---------------------------------------------------------------------------
__global__ void scatter_kernel(const int* __restrict__ src,
                               const int* __restrict__ dst,
                               const float* __restrict__ hs,
                               const float* __restrict__ dis,
                               float* __restrict__ agg) {
    const int total = (N_EDGES + N_NODES) * 8;
    int t = blockIdx.x * blockDim.x + threadIdx.x;
    int stride = gridDim.x * blockDim.x;
    for (; t < total; t += stride) {
        int item = t >> 3;
        int c = t & 7;
        int s, d;
        if (item < N_EDGES) {
            s = src[item];
            d = dst[item];
        } else {
            s = d = item - N_EDGES;
        }
        float sc = dis[d];
        const float4 v = *reinterpret_cast<const float4*>(hs + (size_t)s * HID + c * 4);
        float* a = agg + (size_t)d * HID + c * 4;
        atomicAdd(a + 0, v.x * sc);
        atomicAdd(a + 1, v.y * sc);
        atomicAdd(a + 2, v.z * sc);
        atomicAdd(a + 3, v.w * sc);
    }
}

// ---------------------------------------------------------------------------
// K4: per-feature sum / sumsq over agg rows (stats[0..31]=sum, [32..63]=sumsq)
//     blockDim=256, stride multiple of 32 -> each thread owns one feature
// ---------------------------------------------------------------------------
__global__ void stats_kernel(const float* __restrict__ agg,
                             float* __restrict__ stats) {
    float s = 0.0f, sq = 0.0f;
    int idx = blockIdx.x * blockDim.x + threadIdx.x;
    int stride = gridDim.x * blockDim.x;
    for (; idx < N_NODES * HID; idx += stride) {
        float v = agg[idx];
        s += v;
        sq = fmaf(v, v, sq);
    }
    __shared__ float ss[256];
    __shared__ float ssq[256];
    ss[threadIdx.x] = s;
    ssq[threadIdx.x] = sq;
    __syncthreads();
    if (threadIdx.x < 32) {
        float ts = 0.0f, tq = 0.0f;
#pragma unroll
        for (int g = 0; g < 256; g += 32) {
            ts += ss[g + threadIdx.x];
            tq += ssq[g + threadIdx.x];
        }
        atomicAdd(&stats[threadIdx.x], ts);
        atomicAdd(&stats[32 + threadIdx.x], tq);
    }
}

// ---------------------------------------------------------------------------
// K5: fold BN into affine A,B:  hn = agg*A + B  (A=gamma*invstd, B=beta-mean*A)
// ---------------------------------------------------------------------------
__global__ void finalize_stats_kernel(const float* __restrict__ stats,
                                      const float* __restrict__ gamma,
                                      const float* __restrict__ beta,
                                      float* __restrict__ AB) {
    int f = threadIdx.x;
    if (f < HID) {
        const float invN = 1.0f / (float)N_NODES;
        float mean = stats[f] * invN;
        float var = stats[32 + f] * invN - mean * mean;
        float inv = rsqrtf(var + BN_EPS);
        float A = gamma[f] * inv;
        AB[f] = A;
        AB[32 + f] = beta[f] - mean * A;
    }
}

// ---------------------------------------------------------------------------
// K6: out = relu(agg*A + B) @ W_cls + b_cls
// ---------------------------------------------------------------------------
__global__ void cls_kernel(const float* __restrict__ agg,
                           const float* __restrict__ AB,
                           const float* __restrict__ W_cls,
                           const float* __restrict__ b_cls,
                           float* __restrict__ out) {
    __shared__ float sA[HID];
    __shared__ float sB[HID];
    __shared__ float sW[HID * N_CLS];
    __shared__ float sb[N_CLS];
    if (threadIdx.x < HID) {
        sA[threadIdx.x] = AB[threadIdx.x];
        sB[threadIdx.x] = AB[32 + threadIdx.x];
    }
    for (int t = threadIdx.x; t < HID * N_CLS; t += blockDim.x) sW[t] = W_cls[t];
    if (threadIdx.x < N_CLS) sb[threadIdx.x] = b_cls[threadIdx.x];
    __syncthreads();

    int i = blockIdx.x * blockDim.x + threadIdx.x;
    if (i >= N_NODES) return;

    float acc[N_CLS];
#pragma unroll
    for (int c = 0; c < N_CLS; ++c) acc[c] = sb[c];
#pragma unroll
    for (int f = 0; f < HID; ++f) {
        float t = fmaxf(fmaf(agg[(size_t)i * HID + f], sA[f], sB[f]), 0.0f);
#pragma unroll
        for (int c = 0; c < N_CLS; ++c) acc[c] = fmaf(t, sW[f * N_CLS + c], acc[c]);
    }
#pragma unroll
    for (int c = 0; c < N_CLS; ++c) out[(size_t)i * N_CLS + c] = acc[c];
}

// ---------------------------------------------------------------------------
extern "C" void kernel_launch(void* const* d_in, const int* in_sizes, int n_in,
                              void* d_out, int out_size, void* d_ws, size_t ws_size,
                              hipStream_t stream) {
    const float* x     = (const float*)d_in[0];
    const int*   edge  = (const int*)d_in[1];   // [2, E] int32
    const float* W_emb = (const float*)d_in[2];
    const float* b_emb = (const float*)d_in[3];
    const float* W_gcn = (const float*)d_in[4];
    // d_in[5] = b_gcn: per-feature constant, cancels exactly in BatchNorm -> skip
    const float* gamma = (const float*)d_in[6];
    const float* beta  = (const float*)d_in[7];
    const float* W_cls = (const float*)d_in[8];
    const float* b_cls = (const float*)d_in[9];
    float* out = (float*)d_out;

    // workspace layout
    float* hs    = (float*)d_ws;                       // N*HID
    float* agg   = hs + (size_t)N_NODES * HID;         // N*HID
    float* dis   = agg + (size_t)N_NODES * HID;        // N
    int*   cnt   = (int*)(dis + N_NODES);              // N
    float* stats = (float*)(cnt + N_NODES);            // 64
    float* AB    = stats + 64;                         // 64

    hipMemsetAsync(agg, 0, (size_t)N_NODES * HID * sizeof(float), stream);
    hipMemsetAsync(cnt, 0, (size_t)N_NODES * sizeof(int), stream);
    hipMemsetAsync(stats, 0, 64 * sizeof(float), stream);

    const int* src = edge;
    const int* dst = edge + N_EDGES;

    count_deg_kernel<<<2048, 256, 0, stream>>>(dst, cnt);
    embed_kernel<<<(N_NODES + 255) / 256, 256, 0, stream>>>(x, W_emb, b_emb, W_gcn,
                                                            cnt, hs, dis);
    scatter_kernel<<<2048, 256, 0, stream>>>(src, dst, hs, dis, agg);
    stats_kernel<<<1024, 256, 0, stream>>>(agg, stats);
    finalize_stats_kernel<<<1, 64, 0, stream>>>(stats, gamma, beta, AB);
    cls_kernel<<<(N_NODES + 255) / 256, 256, 0, stream>>>(agg, AB, W_cls, b_cls, out);
}

// Round 2
// 442.826 us; speedup vs baseline: 2.7235x; 2.7235x over previous
//
#include <hip/hip_runtime.h>

#define N_NODES 150000
#define N_EDGES 2400000
#define F_IN    22
#define HID     32
#define N_CLS   6
#define BN_EPS  1e-5f
#define NB_SCAN ((N_NODES + 255) / 256)   // 586 blocks of 256 for the scan

// ---------------------------------------------------------------------------
// K1: in-degree count over dst (self-loop handled as +1 at dis computation)
// ---------------------------------------------------------------------------
__global__ void count_deg_kernel(const int* __restrict__ dst,
                                 int* __restrict__ cnt) {
    int i = blockIdx.x * blockDim.x + threadIdx.x;
    int stride = gridDim.x * blockDim.x;
    for (; i < N_EDGES; i += stride)
        atomicAdd(&cnt[dst[i]], 1);
}

// ---------------------------------------------------------------------------
// K2: per-node h = relu(x@W_emb + b_emb) @ W_gcn ; dis = rsqrt(1+cnt);
//     hs = h * dis   (pre-scaled by source-side norm factor)
// ---------------------------------------------------------------------------
__global__ void embed_kernel(const float* __restrict__ x,
                             const float* __restrict__ W_emb,
                             const float* __restrict__ b_emb,
                             const float* __restrict__ W_gcn,
                             const int*   __restrict__ cnt,
                             float* __restrict__ hs,
                             float* __restrict__ dis) {
    __shared__ float sWe[F_IN * HID];
    __shared__ float sbe[HID];
    __shared__ float sWg[HID * HID];
    for (int t = threadIdx.x; t < F_IN * HID; t += blockDim.x) sWe[t] = W_emb[t];
    if (threadIdx.x < HID) sbe[threadIdx.x] = b_emb[threadIdx.x];
    for (int t = threadIdx.x; t < HID * HID; t += blockDim.x) sWg[t] = W_gcn[t];
    __syncthreads();

    int i = blockIdx.x * blockDim.x + threadIdx.x;
    if (i >= N_NODES) return;

    float xi[F_IN];
#pragma unroll
    for (int f = 0; f < F_IN; ++f) xi[f] = x[(size_t)i * F_IN + f];

    float h1[HID];
#pragma unroll
    for (int j = 0; j < HID; ++j) {
        float acc = sbe[j];
#pragma unroll
        for (int f = 0; f < F_IN; ++f) acc = fmaf(xi[f], sWe[f * HID + j], acc);
        h1[j] = fmaxf(acc, 0.0f);
    }

    float d = rsqrtf(1.0f + (float)cnt[i]);   // deg = 1 (self-loop) + in-count
    dis[i] = d;

#pragma unroll
    for (int j = 0; j < HID; ++j) {
        float acc = 0.0f;
#pragma unroll
        for (int f = 0; f < HID; ++f) acc = fmaf(h1[f], sWg[f * HID + j], acc);
        hs[(size_t)i * HID + j] = acc * d;
    }
}

// ---------------------------------------------------------------------------
// Scan step A: per-256-block sums of cnt
// ---------------------------------------------------------------------------
__global__ void scan_reduce_kernel(const int* __restrict__ cnt,
                                   int* __restrict__ bsum) {
    __shared__ int s[256];
    int i = blockIdx.x * 256 + threadIdx.x;
    s[threadIdx.x] = (i < N_NODES) ? cnt[i] : 0;
    __syncthreads();
#pragma unroll
    for (int o = 128; o > 0; o >>= 1) {
        if (threadIdx.x < o) s[threadIdx.x] += s[threadIdx.x + o];
        __syncthreads();
    }
    if (threadIdx.x == 0) bsum[blockIdx.x] = s[0];
}

// ---------------------------------------------------------------------------
// Scan step B: single-block exclusive scan of the 586 block sums (in place)
// ---------------------------------------------------------------------------
__global__ void scan_blocksums_kernel(int* __restrict__ bsum) {
    __shared__ int s[1024];
    int t = threadIdx.x;
    s[t] = (t < NB_SCAN) ? bsum[t] : 0;
    __syncthreads();
#pragma unroll
    for (int o = 1; o < 1024; o <<= 1) {
        int v = (t >= o) ? s[t - o] : 0;
        __syncthreads();
        s[t] += v;            // inclusive scan
        __syncthreads();
    }
    if (t < NB_SCAN) bsum[t] = (t == 0) ? 0 : s[t - 1];   // exclusive
}

// ---------------------------------------------------------------------------
// Scan step C: off[i] = bsum[blk] + within-block exclusive scan; cur = off copy
// ---------------------------------------------------------------------------
__global__ void scan_final_kernel(const int* __restrict__ cnt,
                                  const int* __restrict__ bsum,
                                  int* __restrict__ off,
                                  int* __restrict__ cur) {
    __shared__ int s[256];
    int i = blockIdx.x * 256 + threadIdx.x;
    int v = (i < N_NODES) ? cnt[i] : 0;
    s[threadIdx.x] = v;
    __syncthreads();
#pragma unroll
    for (int o = 1; o < 256; o <<= 1) {
        int u = (threadIdx.x >= o) ? s[threadIdx.x - o] : 0;
        __syncthreads();
        s[threadIdx.x] += u;   // inclusive
        __syncthreads();
    }
    if (i < N_NODES) {
        int e = bsum[blockIdx.x] + s[threadIdx.x] - v;   // exclusive
        off[i] = e;
        cur[i] = e;
    }
    if (i == N_NODES - 1) off[N_NODES] = N_EDGES;
}

// ---------------------------------------------------------------------------
// K3: bucket edges by dst -> sorted_src  (one int atomic per edge)
// ---------------------------------------------------------------------------
__global__ void fill_csr_kernel(const int* __restrict__ src,
                                const int* __restrict__ dst,
                                int* __restrict__ cur,
                                int* __restrict__ sorted_src) {
    int i = blockIdx.x * blockDim.x + threadIdx.x;
    int stride = gridDim.x * blockDim.x;
    for (; i < N_EDGES; i += stride) {
        int d = dst[i];
        int p = atomicAdd(&cur[d], 1);
        sorted_src[p] = src[i];
    }
}

// ---------------------------------------------------------------------------
// K4: per-node aggregation, no fp32 atomics.
//     agg[i] = (hs[i] + sum_{e in in(i)} hs[src_e]) * dis[i]
//     8 threads per node, float4 per thread.
// ---------------------------------------------------------------------------
__global__ void aggregate_kernel(const int* __restrict__ off,
                                 const int* __restrict__ sorted_src,
                                 const float* __restrict__ hs,
                                 const float* __restrict__ dis,
                                 float* __restrict__ agg) {
    int t = blockIdx.x * blockDim.x + threadIdx.x;
    int node = t >> 3;
    int c = t & 7;
    if (node >= N_NODES) return;

    const float4* hrow = reinterpret_cast<const float4*>(hs);
    float4 acc = hrow[(size_t)node * 8 + c];          // self-loop term
    int b = off[node], e = off[node + 1];
    for (int k = b; k < e; ++k) {
        int s = sorted_src[k];
        float4 v = hrow[(size_t)s * 8 + c];
        acc.x += v.x; acc.y += v.y; acc.z += v.z; acc.w += v.w;
    }
    float d = dis[node];
    acc.x *= d; acc.y *= d; acc.z *= d; acc.w *= d;
    reinterpret_cast<float4*>(agg)[(size_t)node * 8 + c] = acc;
}

// ---------------------------------------------------------------------------
// K5: per-feature sum / sumsq over agg rows (stats[0..31]=sum, [32..63]=sumsq)
// ---------------------------------------------------------------------------
__global__ void stats_kernel(const float* __restrict__ agg,
                             float* __restrict__ stats) {
    float s = 0.0f, sq = 0.0f;
    int idx = blockIdx.x * blockDim.x + threadIdx.x;
    int stride = gridDim.x * blockDim.x;
    for (; idx < N_NODES * HID; idx += stride) {
        float v = agg[idx];
        s += v;
        sq = fmaf(v, v, sq);
    }
    __shared__ float ss[256];
    __shared__ float ssq[256];
    ss[threadIdx.x] = s;
    ssq[threadIdx.x] = sq;
    __syncthreads();
    if (threadIdx.x < 32) {
        float ts = 0.0f, tq = 0.0f;
#pragma unroll
        for (int g = 0; g < 256; g += 32) {
            ts += ss[g + threadIdx.x];
            tq += ssq[g + threadIdx.x];
        }
        atomicAdd(&stats[threadIdx.x], ts);
        atomicAdd(&stats[32 + threadIdx.x], tq);
    }
}

// ---------------------------------------------------------------------------
// K6: fold BN into affine A,B:  hn = agg*A + B
// ---------------------------------------------------------------------------
__global__ void finalize_stats_kernel(const float* __restrict__ stats,
                                      const float* __restrict__ gamma,
                                      const float* __restrict__ beta,
                                      float* __restrict__ AB) {
    int f = threadIdx.x;
    if (f < HID) {
        const float invN = 1.0f / (float)N_NODES;
        float mean = stats[f] * invN;
        float var = stats[32 + f] * invN - mean * mean;
        float inv = rsqrtf(var + BN_EPS);
        float A = gamma[f] * inv;
        AB[f] = A;
        AB[32 + f] = beta[f] - mean * A;
    }
}

// ---------------------------------------------------------------------------
// K7: out = relu(agg*A + B) @ W_cls + b_cls
// ---------------------------------------------------------------------------
__global__ void cls_kernel(const float* __restrict__ agg,
                           const float* __restrict__ AB,
                           const float* __restrict__ W_cls,
                           const float* __restrict__ b_cls,
                           float* __restrict__ out) {
    __shared__ float sA[HID];
    __shared__ float sB[HID];
    __shared__ float sW[HID * N_CLS];
    __shared__ float sb[N_CLS];
    if (threadIdx.x < HID) {
        sA[threadIdx.x] = AB[threadIdx.x];
        sB[threadIdx.x] = AB[32 + threadIdx.x];
    }
    for (int t = threadIdx.x; t < HID * N_CLS; t += blockDim.x) sW[t] = W_cls[t];
    if (threadIdx.x < N_CLS) sb[threadIdx.x] = b_cls[threadIdx.x];
    __syncthreads();

    int i = blockIdx.x * blockDim.x + threadIdx.x;
    if (i >= N_NODES) return;

    float acc[N_CLS];
#pragma unroll
    for (int c = 0; c < N_CLS; ++c) acc[c] = sb[c];
#pragma unroll
    for (int f = 0; f < HID; ++f) {
        float t = fmaxf(fmaf(agg[(size_t)i * HID + f], sA[f], sB[f]), 0.0f);
#pragma unroll
        for (int c = 0; c < N_CLS; ++c) acc[c] = fmaf(t, sW[f * N_CLS + c], acc[c]);
    }
#pragma unroll
    for (int c = 0; c < N_CLS; ++c) out[(size_t)i * N_CLS + c] = acc[c];
}

// ---------------------------------------------------------------------------
extern "C" void kernel_launch(void* const* d_in, const int* in_sizes, int n_in,
                              void* d_out, int out_size, void* d_ws, size_t ws_size,
                              hipStream_t stream) {
    const float* x     = (const float*)d_in[0];
    const int*   edge  = (const int*)d_in[1];   // [2, E] int32
    const float* W_emb = (const float*)d_in[2];
    const float* b_emb = (const float*)d_in[3];
    const float* W_gcn = (const float*)d_in[4];
    // d_in[5] = b_gcn: per-feature constant, cancels exactly in BatchNorm -> skip
    const float* gamma = (const float*)d_in[6];
    const float* beta  = (const float*)d_in[7];
    const float* W_cls = (const float*)d_in[8];
    const float* b_cls = (const float*)d_in[9];
    float* out = (float*)d_out;

    // workspace layout (~51 MB)
    float* hs         = (float*)d_ws;                         // N*HID
    float* agg        = hs + (size_t)N_NODES * HID;           // N*HID
    float* dis        = agg + (size_t)N_NODES * HID;          // N
    int*   cnt        = (int*)(dis + N_NODES);                // N
    int*   off        = cnt + N_NODES;                        // N+1
    int*   cur        = off + N_NODES + 1;                    // N
    int*   bsum       = cur + N_NODES;                        // 1024
    int*   sorted_src = bsum + 1024;                          // E
    float* stats      = (float*)(sorted_src + N_EDGES);       // 64
    float* AB         = stats + 64;                           // 64

    hipMemsetAsync(cnt, 0, (size_t)N_NODES * sizeof(int), stream);
    hipMemsetAsync(stats, 0, 64 * sizeof(float), stream);

    const int* src = edge;
    const int* dst = edge + N_EDGES;

    count_deg_kernel<<<2048, 256, 0, stream>>>(dst, cnt);
    embed_kernel<<<(N_NODES + 255) / 256, 256, 0, stream>>>(x, W_emb, b_emb, W_gcn,
                                                            cnt, hs, dis);
    scan_reduce_kernel<<<NB_SCAN, 256, 0, stream>>>(cnt, bsum);
    scan_blocksums_kernel<<<1, 1024, 0, stream>>>(bsum);
    scan_final_kernel<<<NB_SCAN, 256, 0, stream>>>(cnt, bsum, off, cur);
    fill_csr_kernel<<<2048, 256, 0, stream>>>(src, dst, cur, sorted_src);
    aggregate_kernel<<<(N_NODES * 8 + 255) / 256, 256, 0, stream>>>(off, sorted_src,
                                                                    hs, dis, agg);
    stats_kernel<<<1024, 256, 0, stream>>>(agg, stats);
    finalize_stats_kernel<<<1, 64, 0, stream>>>(stats, gamma, beta, AB);
    cls_kernel<<<(N_NODES + 255) / 256, 256, 0, stream>>>(agg, AB, W_cls, b_cls, out);
}